// Round 11
// baseline (118.208 us; speedup 1.0000x reference)
//
#include <hip/hip_runtime.h>

typedef __attribute__((ext_vector_type(8))) short bf16x8;   // 8 bf16
typedef __attribute__((ext_vector_type(4))) float f32x4;    // MFMA acc (16x16)
typedef __attribute__((ext_vector_type(8))) int   i32x8;    // f8f6f4 operand
typedef unsigned short u16;
typedef unsigned int   u32;
typedef unsigned char  u8;

#define DEVI __device__ __forceinline__

// fp32 -> bf16 round-to-nearest-even
DEVI u16 f2bf(float f) {
    u32 u = __float_as_uint(f);
    u32 r = (u + 0x7FFFu + ((u >> 16) & 1u)) >> 16;
    return (u16)r;
}
DEVI u32 pk(float a, float b) {
    return (u32)f2bf(a) | ((u32)f2bf(b) << 16);
}
DEVI float bflo(u32 w) { return __uint_as_float((w & 0xFFFFu) << 16); }
DEVI float bfhi(u32 w) { return __uint_as_float(w & 0xFFFF0000u); }
// 4x fp32 -> 4x fp8 e4m3 (OCP) packed in one dword
DEVI u32 cvt8(float a, float b, float c, float d) {
    int w = 0;
    w = __builtin_amdgcn_cvt_pk_fp8_f32(a, b, w, false);
    w = __builtin_amdgcn_cvt_pk_fp8_f32(c, d, w, true);
    return (u32)w;
}
// fp4 e2m1 encode of x in [0,1) with block scale 2^-2: code for t = 4x,
// RTN onto levels {0,0.5,1,1.5,2,3,4} = codes 0..6 (level 6.0/code 7 unused).
DEVI u32 enc1(float x) {
    float t = x * 4.0f;
    u32 c;
    if (t < 1.75f) c = (u32)(int)(t + t + 0.5f);
    else           c = (t < 2.5f) ? 4u : ((t < 3.5f) ? 5u : 6u);
    return c;
}
DEVI u32 enc8(float4 a, float4 b) {   // 8 elems -> 8 nibbles, little-endian
    return enc1(a.x) | (enc1(a.y) << 4) | (enc1(a.z) << 8) | (enc1(a.w) << 12) |
           (enc1(b.x) << 16) | (enc1(b.y) << 20) | (enc1(b.z) << 24) |
           (enc1(b.w) << 28);
}
// async global->LDS, 16B per lane (global_load_lds_dwordx4)
DEVI void gld16(const void* g, void* l) {
    __builtin_amdgcn_global_load_lds(
        (const __attribute__((address_space(1))) u32*)g,
        (__attribute__((address_space(3))) u32*)l, 16, 0, 0);
}

#define SCALE_A 0x7D7D7D7D   // e8m0 2^-2 per 32-elem block (uniform -> opsel-immune)
#define SCALE_B 0x7F7F7F7F   // e8m0 1.0

// ---------------------------------------------------------------------------
// Kernel 1: d[i] = rsqrt(rowsum(adj)); write fp4 PRE-SWIZZLED adjacency.
// ADJH layout: row-major, 4096 B/row; per 64-B k-group (128 elems), 4 slots
// of 16 B; physical slot = logical ^ ((row>>1)&3)  [2-way-free on ds_read].
// ---------------------------------------------------------------------------
template<bool WRITE_H>
__global__ __launch_bounds__(256)
void deg_k(const float* __restrict__ adj, float* __restrict__ dvec,
           u8* __restrict__ adjh) {
    const int row = blockIdx.x;
    const int t   = threadIdx.x;
    const float4* p = (const float4*)(adj + (long long)row * 8192);
    float s = 0.f;
#pragma unroll
    for (int i = 0; i < 2; ++i) {
        int c = t + i * 256;                 // 16-elem chunk index in [0,512)
        float4 v0 = p[4 * c + 0];
        float4 v1 = p[4 * c + 1];
        float4 v2 = p[4 * c + 2];
        float4 v3 = p[4 * c + 3];
        s += (v0.x + v0.y) + (v0.z + v0.w) + (v1.x + v1.y) + (v1.z + v1.w) +
             (v2.x + v2.y) + (v2.z + v2.w) + (v3.x + v3.y) + (v3.z + v3.w);
        if constexpr (WRITE_H) {
            u32 w0 = enc8(v0, v1);           // elems 0..7  of chunk
            u32 w1 = enc8(v2, v3);           // elems 8..15
            int grp = c >> 3, qq = c & 7;    // 64B group, 8B sub-chunk
            int phys = (qq >> 1) ^ ((row >> 1) & 3);
            *(uint2*)(adjh + (long long)row * 4096 + grp * 64 + phys * 16 +
                      (qq & 1) * 8) = make_uint2(w0, w1);
        }
    }
#pragma unroll
    for (int off = 32; off; off >>= 1) s += __shfl_down(s, off, 64);
    __shared__ float red[4];
    if ((t & 63) == 0) red[t >> 6] = s;
    __syncthreads();
    if (t == 0) dvec[row] = 1.0f / sqrtf(red[0] + red[1] + red[2] + red[3]);
}

// ---------------------------------------------------------------------------
// Small MFMA GEMM, transposed output repack to fp8, pre-swizzled for the fp4
// aggregates' B-operand read patterns:
//   SWZ 0 (B1): 16B slots in 128B j-groups, physical = logical ^ (n&7)
//   SWZ 1 (B2): 32B slots in 128B j-groups, physical = logical ^ (n&3)
//   AMODE 0: A fp32.  AMODE 2: A = relu(d/64 * sum4 bf16 H1P parts).
// ---------------------------------------------------------------------------
template<int BM, int BN, int WM, int WN, int AMODE, int SC, int SWZ>
__global__ __launch_bounds__(256)
void gemmsw_k(const void* __restrict__ Ap, int lda,
              const float* __restrict__ Bp, int ldb,
              u8* __restrict__ Op, int ldo,
              const float* __restrict__ dvec,
              int mtiles, int ntiles, int klen) {
    constexpr int BK  = 64;
    constexpr int WTM = BM / WM, WTN = BN / WN;
    constexpr int FM  = WTM / 16, FN = WTN / 16;
    constexpr int SA  = BM * BK;   // u16 elements
    constexpr int SB  = BN * BK;
    __shared__ __align__(16) u16 lds[SA + SB];

    const int t   = threadIdx.x;
    const int mt  = blockIdx.x % mtiles;
    const int nt  = (blockIdx.x / mtiles) % ntiles;
    const int m0  = mt * BM;
    const int n0  = nt * BN;

    const int lane = t & 63, lrow = lane & 15, kg = lane >> 4;
    const int wave = t >> 6;
    const int wr0  = (wave % WM) * WTM;
    const int wc0  = (wave / WM) * WTN;

    f32x4 acc[FM][FN] = {};

    auto stage = [&](int k0) {
        char* AB = (char*)lds;
        char* BB = (char*)(lds + SA);
        if constexpr (AMODE == 0) {
            constexpr int NA = BM * 16 / 256;
#pragma unroll
            for (int i = 0; i < NA; ++i) {
                int idx = t + i * 256, r = idx >> 4, c = idx & 15;
                float4 v = *(const float4*)((const float*)Ap +
                            (long long)(m0 + r) * lda + k0 + c * 4);
                int off = r * 128 + ((((c >> 1) ^ (r & 7)) << 4) | ((c & 1) << 3));
                *(uint2*)(AB + off) = make_uint2(pk(v.x, v.y), pk(v.z, v.w));
            }
        } else {   // AMODE 2: fused 4-part BF16 reduce + relu + d/64
            constexpr int NA = BM * 8 / 256;
#pragma unroll
            for (int i = 0; i < NA; ++i) {
                int idx = t + i * 256, r = idx >> 3, j8 = idx & 7;
                const u16* base = (const u16*)Ap +
                                  (long long)(m0 + r) * lda + k0 + j8 * 8;
                float s[8] = {};
#pragma unroll
                for (int pp = 0; pp < 4; ++pp) {
                    uint4 v = *(const uint4*)(base + (long long)pp * 2097152);
                    s[0] += bflo(v.x); s[1] += bfhi(v.x);
                    s[2] += bflo(v.y); s[3] += bfhi(v.y);
                    s[4] += bflo(v.z); s[5] += bfhi(v.z);
                    s[6] += bflo(v.w); s[7] += bfhi(v.w);
                }
                float dv = dvec[m0 + r] * 0.015625f;
                uint4 w = make_uint4(
                    pk(fmaxf(s[0], 0.f) * dv, fmaxf(s[1], 0.f) * dv),
                    pk(fmaxf(s[2], 0.f) * dv, fmaxf(s[3], 0.f) * dv),
                    pk(fmaxf(s[4], 0.f) * dv, fmaxf(s[5], 0.f) * dv),
                    pk(fmaxf(s[6], 0.f) * dv, fmaxf(s[7], 0.f) * dv));
                *(uint4*)(AB + r * 128 + ((j8 ^ (r & 7)) << 4)) = w;
            }
        }
        {   // B fp32
            constexpr int NB = BN * 16 / 256;
#pragma unroll
            for (int i = 0; i < NB; ++i) {
                int idx = t + i * 256, r = idx >> 4, c = idx & 15;
                float4 v = *(const float4*)(Bp + (long long)(n0 + r) * ldb + k0 + c * 4);
                int off = r * 128 + ((((c >> 1) ^ (r & 7)) << 4) | ((c & 1) << 3));
                *(uint2*)(BB + off) = make_uint2(pk(v.x, v.y), pk(v.z, v.w));
            }
        }
    };

    auto compute = [&]() {
        const char* AB = (const char*)lds;
        const char* BB = (const char*)(lds + SA);
#pragma unroll
        for (int s = 0; s < 2; ++s) {
            bf16x8 a[FM]; bf16x8 b[FN];
#pragma unroll
            for (int f = 0; f < FM; ++f) {
                int r = wr0 + f * 16 + lrow;
                a[f] = *(const bf16x8*)(AB + r * 128 + (((s * 4 + kg) ^ (r & 7)) << 4));
            }
#pragma unroll
            for (int f = 0; f < FN; ++f) {
                int r = wc0 + f * 16 + lrow;
                b[f] = *(const bf16x8*)(BB + r * 128 + (((s * 4 + kg) ^ (r & 7)) << 4));
            }
#pragma unroll
            for (int i = 0; i < FM; ++i)
#pragma unroll
                for (int j = 0; j < FN; ++j)
                    acc[i][j] = __builtin_amdgcn_mfma_f32_16x16x32_bf16(
                        a[i], b[j], acc[i][j], 0, 0, 0);
        }
    };

    const int NT = klen / BK;
    for (int tt = 0; tt < NT; ++tt) {
        stage(tt * BK);
        __syncthreads();
        compute();
        __syncthreads();
    }

    // ---- transposed fp8 repack epilogue (LDS bounce, padded stride BN+1)
    __syncthreads();
    float* LF = (float*)lds;
    constexpr int LDSBYTES = (SA + SB) * 2;
    constexpr int LFS = BN + 1;
    constexpr int PHR = (BM * LFS * 4 <= LDSBYTES) ? BM : (BM / 2);
    static_assert(PHR * LFS * 4 <= LDSBYTES, "repack phase too big");
    constexpr int NPH = BM / PHR;
    constexpr int MG  = PHR / 16;
#pragma unroll
    for (int ph = 0; ph < NPH; ++ph) {
        if (ph) __syncthreads();
#pragma unroll
        for (int i = 0; i < FM; ++i) {
            int mlb = wr0 + i * 16 + kg * 4;
            if (mlb >= ph * PHR && mlb < (ph + 1) * PHR) {
#pragma unroll
                for (int rr = 0; rr < 4; ++rr) {
                    float dv = dvec[m0 + mlb + rr] * (float)SC;
#pragma unroll
                    for (int j = 0; j < FN; ++j)
                        LF[(mlb - ph * PHR + rr) * LFS + wc0 + j * 16 + lrow] =
                            acc[i][j][rr] * dv;
                }
            }
        }
        __syncthreads();
        constexpr int CHK = BN * MG;
#pragma unroll
        for (int it = 0; it < (CHK + 255) / 256; ++it) {
            int q = t + it * 256;
            if (q < CHK) {
                int n = q / MG, mg = q % MG;
                float f[16];
#pragma unroll
                for (int e = 0; e < 16; ++e) f[e] = LF[(mg * 16 + e) * LFS + n];
                uint4 w = make_uint4(cvt8(f[0], f[1], f[2], f[3]),
                                     cvt8(f[4], f[5], f[6], f[7]),
                                     cvt8(f[8], f[9], f[10], f[11]),
                                     cvt8(f[12], f[13], f[14], f[15]));
                int gj = (m0 >> 4) + ph * MG + mg;   // 16-elem chunk along j
                int ng = n0 + n;
                long long byte;
                if constexpr (SWZ == 0)
                    byte = (long long)ng * ldo + (gj >> 3) * 128 +
                           (((gj & 7) ^ (ng & 7)) << 4);
                else
                    byte = (long long)ng * ldo + (gj >> 3) * 128 +
                           ((((gj >> 1) & 3) ^ (ng & 3)) << 5) + ((gj & 1) << 4);
                *(uint4*)(Op + byte) = w;
            }
        }
    }
}

// ---------------------------------------------------------------------------
// Layer-1 aggregate, MX: H1P[kp][i][h] = bf16( sum_k adj_fp4[i,k] * b1_fp8[h,k] )
// mfma_scale_f32_16x16x128_f8f6f4, A=fp4 (cbsz=4, scale 2^-2), B=fp8 (blgp=0,
// scale 1.0). BM=64, BN=256, BK=128, 4 waves, gld16 dbuf, vmcnt(9).
// (R10 verbatim — measured-good, do not touch.)
// ---------------------------------------------------------------------------
__global__ __launch_bounds__(256)
void agg1f4_k(const u8* __restrict__ A, const u8* __restrict__ B,
              u16* __restrict__ Op, int mtiles, int klen, long long kstride) {
    constexpr int BK = 128;
    constexpr int ABUF = 64 * 64;          // 4096 B  (64 rows x 64 B fp4)
    constexpr int BBUF = 256 * 128;        // 32768 B (256 rows x 128 B fp8)
    constexpr int BUF  = ABUF + BBUF;      // 36864 B
    __shared__ __align__(16) u8 lds[2 * BUF];   // 72 KB -> 2 blocks/CU

    const int t  = threadIdx.x;
    const int mt = blockIdx.x % mtiles;
    const int kp = blockIdx.x / mtiles;
    const int m0 = mt * 64;
    const long long k00 = (long long)kp * klen;     // element offset along k
    const int lane = t & 63, lrow = lane & 15, kg = lane >> 4;
    const int wc0  = (t >> 6) * 64;

    f32x4 acc[4][4] = {};

    auto stage = [&](long long k0, int pb) {
        u8* dst = lds + pb * BUF;
        {   // A fp4: 256 chunks = 64 rows x 4 slots (global pre-swizzled)
            int c = t, r = c >> 2;
            gld16(A + (long long)(m0 + r) * 4096 + (k0 >> 1) + (c & 3) * 16,
                  dst + c * 16);
        }
#pragma unroll
        for (int i = 0; i < 8; ++i) {   // B fp8: 2048 chunks = 256 rows x 8 slots
            int cb = t + i * 256, rb = cb >> 3;
            gld16(B + (long long)rb * 8192 + k0 + (cb & 7) * 16,
                  dst + ABUF + cb * 16);
        }
    };

    auto compute = [&](int pb) {
        const u8* Ab = lds + pb * BUF;
        const u8* Bb = Ab + ABUF;
        i32x8 a[4], b[4];
#pragma unroll
        for (int f = 0; f < 4; ++f) {
            int ar = f * 16 + lrow;
            uint4 aw = *(const uint4*)(Ab + ar * 64 +
                        ((kg ^ ((ar >> 1) & 3)) << 4));
            a[f] = i32x8{(int)aw.x, (int)aw.y, (int)aw.z, (int)aw.w, 0, 0, 0, 0};
        }
#pragma unroll
        for (int f = 0; f < 4; ++f) {
            int rb = wc0 + f * 16 + lrow;
            uint4 b0 = *(const uint4*)(Bb + rb * 128 +
                         (((2 * kg) ^ (rb & 7)) << 4));
            uint4 b1 = *(const uint4*)(Bb + rb * 128 +
                         (((2 * kg + 1) ^ (rb & 7)) << 4));
            b[f] = i32x8{(int)b0.x, (int)b0.y, (int)b0.z, (int)b0.w,
                         (int)b1.x, (int)b1.y, (int)b1.z, (int)b1.w};
        }
#pragma unroll
        for (int i = 0; i < 4; ++i)
#pragma unroll
            for (int j = 0; j < 4; ++j)
                acc[i][j] = __builtin_amdgcn_mfma_scale_f32_16x16x128_f8f6f4(
                    a[i], b[j], acc[i][j], 4, 0, 0, SCALE_A, 0, SCALE_B);
    };

    stage(k00, 0);
    const int NT = klen / BK;
    for (int tt = 0; tt < NT; ++tt) {
        const int p = tt & 1;
        if (tt + 1 < NT) {
            stage(k00 + (long long)(tt + 1) * BK, p ^ 1);
            asm volatile("s_waitcnt vmcnt(9)" ::: "memory");
        } else {
            asm volatile("s_waitcnt vmcnt(0)" ::: "memory");
        }
        __builtin_amdgcn_s_barrier();
        compute(p);
        asm volatile("" ::: "memory");
        __builtin_amdgcn_s_barrier();
    }

#pragma unroll
    for (int i = 0; i < 4; ++i)
#pragma unroll
        for (int j = 0; j < 4; ++j)
#pragma unroll
            for (int rr = 0; rr < 4; ++rr) {
                int m = m0 + i * 16 + kg * 4 + rr;
                int n = wc0 + j * 16 + lrow;
                Op[kp * kstride + (long long)m * 256 + n] = f2bf(acc[i][j][rr]);
            }
}

// ---------------------------------------------------------------------------
// Layer-2 aggregate, MX: H2P[kp][i][c] = sum_k adj_fp4[i,k] * b2_fp8[c,k]
// R11: split-K 4 -> 8 (KLEN 1024, 1024 blocks). Mechanism: each K-step is a
// full HBM round-trip (1 gld16/thread, vmcnt(1), barrier) -- latency-serial
// per block. LDS drops to 24 KB -> ~4 resident blocks/CU -> 4-deep block-TLP
// hides the A-stream latency. B-prestage halves to 16 rows x 1024 B.
// ---------------------------------------------------------------------------
__global__ __launch_bounds__(256)
void agg2f4_k(const u8* __restrict__ A, const u8* __restrict__ B,
              float* __restrict__ Op, int mtiles) {
    constexpr int KLEN = 1024, BK = 128, NT = KLEN / BK;   // 8 steps
    constexpr int ABUF = 64 * 64;                          // 4096 B
    __shared__ __align__(16) u8 lds[2 * ABUF + 16 * KLEN]; // 24 KB

    const int t  = threadIdx.x;
    const int mt = blockIdx.x % mtiles;
    const int kp = blockIdx.x / mtiles;
    const int m0 = mt * 64;
    const long long k00 = (long long)kp * KLEN;
    const int lane = t & 63, lrow = lane & 15, kg = lane >> 4;
    const int wr0  = (t >> 6) * 16;
    u8* Bl = lds + 2 * ABUF;

    // prestage whole B K-slice: 16 rows x 1024 B (pre-swizzled 32B slots)
#pragma unroll
    for (int i = 0; i < 4; ++i) {
        int c = t + i * 256, rb = c >> 6;
        gld16(B + (long long)rb * 8192 + k00 + (c & 63) * 16, Bl + c * 16);
    }

    auto stageA = [&](long long k0, int pb) {
        int c = t, r = c >> 2;
        gld16(A + (long long)(m0 + r) * 4096 + (k0 >> 1) + (c & 3) * 16,
              lds + pb * ABUF + c * 16);
    };

    f32x4 acc = {};
    stageA(k00, 0);
    for (int tt = 0; tt < NT; ++tt) {
        const int p = tt & 1;
        if (tt + 1 < NT) {
            stageA(k00 + (long long)(tt + 1) * BK, p ^ 1);
            asm volatile("s_waitcnt vmcnt(1)" ::: "memory");
        } else {
            asm volatile("s_waitcnt vmcnt(0)" ::: "memory");
        }
        __builtin_amdgcn_s_barrier();
        const u8* Ab = lds + p * ABUF;
        int ra = wr0 + lrow;
        uint4 aw = *(const uint4*)(Ab + ra * 64 + ((kg ^ ((ra >> 1) & 3)) << 4));
        i32x8 a = i32x8{(int)aw.x, (int)aw.y, (int)aw.z, (int)aw.w, 0, 0, 0, 0};
        const u8* bbase = Bl + lrow * KLEN + tt * 128 + ((kg ^ (lrow & 3)) << 5);
        uint4 b0 = *(const uint4*)(bbase);
        uint4 b1 = *(const uint4*)(bbase + 16);
        i32x8 b = i32x8{(int)b0.x, (int)b0.y, (int)b0.z, (int)b0.w,
                        (int)b1.x, (int)b1.y, (int)b1.z, (int)b1.w};
        acc = __builtin_amdgcn_mfma_scale_f32_16x16x128_f8f6f4(
                a, b, acc, 4, 0, 0, SCALE_A, 0, SCALE_B);
        asm volatile("" ::: "memory");
        __builtin_amdgcn_s_barrier();
    }

#pragma unroll
    for (int rr = 0; rr < 4; ++rr) {
        int m = m0 + wr0 + kg * 4 + rr;
        Op[(long long)kp * 131072 + (long long)m * 16 + lrow] = acc[rr];
    }
}

// ---------------------------------------------------------------------------
// out[i][c] = log_softmax(scl * d[i] * sum_p H2p[p][i][c])
// ---------------------------------------------------------------------------
__global__ __launch_bounds__(256)
void final_k(const float* __restrict__ H, const float* __restrict__ dvec,
             float* __restrict__ out, int parts, float scl) {
    int i = blockIdx.x * 256 + threadIdx.x;
    float z[16];
#pragma unroll
    for (int c = 0; c < 16; c += 4) {
        float4 v = *(const float4*)(H + (long long)i * 16 + c);
        z[c] = v.x; z[c + 1] = v.y; z[c + 2] = v.z; z[c + 3] = v.w;
    }
    for (int p = 1; p < parts; ++p) {
#pragma unroll
        for (int c = 0; c < 16; c += 4) {
            float4 v = *(const float4*)(H + (long long)p * 131072 +
                                        (long long)i * 16 + c);
            z[c] += v.x; z[c + 1] += v.y; z[c + 2] += v.z; z[c + 3] += v.w;
        }
    }
    float dv = dvec[i] * scl;
    float m = -1e30f;
#pragma unroll
    for (int c = 0; c < 16; ++c) { z[c] *= dv; m = fmaxf(m, z[c]); }
    float l = 0.f;
#pragma unroll
    for (int c = 0; c < 16; ++c) l += __expf(z[c] - m);
    float lse = m + __logf(l);
#pragma unroll
    for (int c = 0; c < 16; c += 4) {
        float4 v;
        v.x = z[c] - lse; v.y = z[c + 1] - lse;
        v.z = z[c + 2] - lse; v.w = z[c + 3] - lse;
        *(float4*)(out + (long long)i * 16 + c) = v;
    }
}

// ===========================================================================
// Fallback path (small workspace): R2's bf16 kernels, kept verbatim.
// ===========================================================================
template<int BM, int BN, int WM, int WN, bool AF32, bool BF32, int EPI>
__global__ __launch_bounds__(256)
void gemm_old_k(const void* __restrict__ Ap, int lda,
                const void* __restrict__ Bp, int ldb,
                void* __restrict__ Op, int ldo,
                const float* __restrict__ dvec,
                int mtiles, int ntiles, int klen, long long kstride) {
    constexpr int BK  = 64;
    constexpr int WTM = BM / WM, WTN = BN / WN;
    constexpr int FM  = WTM / 16, FN = WTN / 16;
    constexpr int SA  = BM * BK;
    constexpr int SB  = BN * BK;
    __shared__ __align__(16) u16 lds[SA + SB];

    const int t   = threadIdx.x;
    const int bid = blockIdx.x;
    const int mt  = bid % mtiles;
    const int nt  = (bid / mtiles) % ntiles;
    const int kp  = bid / (mtiles * ntiles);
    const int m0  = mt * BM, n0 = nt * BN;
    const long long k00 = (long long)kp * klen;

    const float* Af = (const float*)Ap;
    const u16*   Ah = (const u16*)Ap;
    const float* Bf = (const float*)Bp;
    const u16*   Bh = (const u16*)Bp;

    f32x4 acc[FM][FN] = {};

    const int lane = t & 63;
    const int lrow = lane & 15, kg = lane >> 4;
    const int wave = t >> 6;
    const int wr0  = (wave % WM) * WTM;
    const int wc0  = (wave / WM) * WTN;

    auto stage = [&](long long k0) {
        char* AB = (char*)lds;
        char* BB = (char*)(lds + SA);
        if constexpr (AF32) {
            constexpr int NA = BM * 16 / 256;
#pragma unroll
            for (int i = 0; i < NA; ++i) {
                int idx = t + i * 256, r = idx >> 4, c = idx & 15;
                float4 v = *(const float4*)(Af + (long long)(m0 + r) * lda + k0 + c * 4);
                int off = r * 128 + ((((c >> 1) ^ (r & 7)) << 4) | ((c & 1) << 3));
                *(uint2*)(AB + off) = make_uint2(pk(v.x, v.y), pk(v.z, v.w));
            }
        } else {
            constexpr int NA = (BM * 8 + 255) / 256;
#pragma unroll
            for (int i = 0; i < NA; ++i) {
                int idx = t + i * 256;
                if (BM * 8 >= 256 || idx < BM * 8) {
                    int r = idx >> 3, j = idx & 7;
                    uint4 v = *(const uint4*)(Ah + (long long)(m0 + r) * lda + k0 + j * 8);
                    *(uint4*)(AB + r * 128 + ((j ^ (r & 7)) << 4)) = v;
                }
            }
        }
        if constexpr (BF32) {
            constexpr int NB = BN * 16 / 256;
#pragma unroll
            for (int i = 0; i < NB; ++i) {
                int idx = t + i * 256, r = idx >> 4, c = idx & 15;
                float4 v = *(const float4*)(Bf + (long long)(n0 + r) * ldb + k0 + c * 4);
                int off = r * 128 + ((((c >> 1) ^ (r & 7)) << 4) | ((c & 1) << 3));
                *(uint2*)(BB + off) = make_uint2(pk(v.x, v.y), pk(v.z, v.w));
            }
        } else {
            constexpr int NB = (BN * 8 + 255) / 256;
#pragma unroll
            for (int i = 0; i < NB; ++i) {
                int idx = t + i * 256;
                if (BN * 8 >= 256 || idx < BN * 8) {
                    int r = idx >> 3, j = idx & 7;
                    uint4 v = *(const uint4*)(Bh + (long long)(n0 + r) * ldb + k0 + j * 8);
                    *(uint4*)(BB + r * 128 + ((j ^ (r & 7)) << 4)) = v;
                }
            }
        }
    };

    auto compute = [&]() {
        const char* AB = (const char*)lds;
        const char* BB = (const char*)(lds + SA);
#pragma unroll
        for (int s = 0; s < 2; ++s) {
            bf16x8 a[FM]; bf16x8 b[FN];
#pragma unroll
            for (int f = 0; f < FM; ++f) {
                int r = wr0 + f * 16 + lrow;
                a[f] = *(const bf16x8*)(AB + r * 128 + (((s * 4 + kg) ^ (r & 7)) << 4));
            }
#pragma unroll
            for (int f = 0; f < FN; ++f) {
                int r = wc0 + f * 16 + lrow;
                b[f] = *(const bf16x8*)(BB + r * 128 + (((s * 4 + kg) ^ (r & 7)) << 4));
            }
#pragma unroll
            for (int i = 0; i < FM; ++i)
#pragma unroll
                for (int j = 0; j < FN; ++j)
                    acc[i][j] = __builtin_amdgcn_mfma_f32_16x16x32_bf16(
                        a[i], b[j], acc[i][j], 0, 0, 0);
        }
    };

    const int NT = klen / BK;
    for (int tt = 0; tt < NT; ++tt) {
        stage(k00 + (long long)tt * BK);
        __syncthreads();
        compute();
        __syncthreads();
    }

#pragma unroll
    for (int i = 0; i < FM; ++i)
#pragma unroll
        for (int j = 0; j < FN; ++j)
#pragma unroll
            for (int r = 0; r < 4; ++r) {
                int m = m0 + wr0 + i * 16 + kg * 4 + r;
                int n = n0 + wc0 + j * 16 + lrow;
                float v = acc[i][j][r];
                if constexpr (EPI == 0) {
                    ((float*)Op)[kp * kstride + (long long)m * ldo + n] = v;
                } else if constexpr (EPI == 1) {
                    ((u16*)Op)[(long long)m * ldo + n] = f2bf(v * dvec[n]);
                } else {
                    ((u16*)Op)[(long long)m * ldo + n] =
                        f2bf(fmaxf(v * dvec[m], 0.0f));
                }
            }
}

__global__ __launch_bounds__(256)
void reduce1_k(const float* __restrict__ H, const float* __restrict__ dvec,
               u16* __restrict__ x1, int parts) {
    long long i = ((long long)blockIdx.x * 256 + threadIdx.x) * 4;
    float4 s = *(const float4*)(H + i);
    for (int p = 1; p < parts; ++p) {
        float4 v = *(const float4*)(H + (long long)p * 2097152 + i);
        s.x += v.x; s.y += v.y; s.z += v.z; s.w += v.w;
    }
    float dv = dvec[i >> 8];
    *(uint2*)(x1 + i) = make_uint2(
        pk(fmaxf(s.x * dv, 0.f), fmaxf(s.y * dv, 0.f)),
        pk(fmaxf(s.z * dv, 0.f), fmaxf(s.w * dv, 0.f)));
}

// ---------------------------------------------------------------------------
extern "C" void kernel_launch(void* const* d_in, const int* in_sizes, int n_in,
                              void* d_out, int out_size, void* d_ws, size_t ws_size,
                              hipStream_t stream) {
    (void)in_sizes; (void)n_in; (void)out_size;
    const float* X   = (const float*)d_in[0];   // [8192,512]
    const float* ADJ = (const float*)d_in[1];   // [8192,8192]
    const float* W1  = (const float*)d_in[2];   // [256,512]
    const float* W2  = (const float*)d_in[3];   // [16,256]
    float* out = (float*)d_out;
    char*  ws  = (char*)d_ws;

    if (ws_size >= 56786944ULL) {
        // ---- fast path: MX-fp4 pre-swizzled adjacency + scaled-MFMA aggregates
        float* dvec = (float*)(ws + 0);           //  32 KB
        u8*    B1   = (u8*)(ws + 32768);          //   2 MB [256 h][8192 j] fp8 swz
        u8*    B2   = (u8*)(ws + 2129920);        // 128 KB [16 c][8192 j] fp8 swz
        u16*   H1P  = (u16*)(ws + 2260992);       //  16 MB [4][8192][256] bf16
        float* H2P  = (float*)(ws + 19038208);    //   4 MB [8][8192][16]
        u8*    ADJH = (u8*)(ws + 23232512);       //  32 MB [8192][4096 B] fp4 swz

        // 1) degrees + fp4 swizzled adjacency
        deg_k<true><<<8192, 256, 0, stream>>>(ADJ, dvec, ADJH);

        // 2) B1[h][j] = fp8(64 * d_j * (X @ W1^T)[j,h]) — SWZ0 (B1-read pattern)
        gemmsw_k<64, 128, 1, 4, 0, 64, 0><<<256, 256, 0, stream>>>(
            X, 512, W1, 512, B1, 8192, dvec, 128, 2, 512);

        // 3) H1P = ADJH(fp4) @ B1^T(fp8), bf16 partials (split-K=4)
        agg1f4_k<<<512, 256, 0, stream>>>(ADJH, B1, H1P, 128, 2048, 2097152LL);

        // 4) B2[c][j] = fp8(8192 * d_j * relu(d/64 * sum4 H1P) @ W2^T) — SWZ1
        gemmsw_k<64, 16, 4, 1, 2, 8192, 1><<<128, 256, 0, stream>>>(
            H1P, 256, W2, 256, B2, 8192, dvec, 128, 1, 256);

        // 5) H2P = ADJH(fp4) @ B2^T(fp8)  (R11: split-K=8, 1024 blocks)
        agg2f4_k<<<1024, 256, 0, stream>>>(ADJH, B2, H2P, 128);

        // 6) d_i/8192 scale + log-softmax (8 parts)
        final_k<<<32, 256, 0, stream>>>(H2P, dvec, out, 8, 1.0f / 8192.0f);
        return;
    }

    // ---- fallback: fp32-adjacency bf16 path (R2 structure)
    float* dvec = (float*)(ws + 0);
    u16*   B1   = (u16*)(ws + 32768);
    u16*   X1   = (u16*)(ws + 4227072);
    u16*   B2   = (u16*)(ws + 8421376);
    float* H2P  = (float*)(ws + 8683520);
    float* H1P  = (float*)(ws + 12877824);

    int SK1, SK2; bool useH1P;
    if      (ws_size >= 46432256ULL)  { SK1 = 4; SK2 = 8; useH1P = true;  }
    else if (ws_size >= 29655040ULL)  { SK1 = 2; SK2 = 8; useH1P = true;  }
    else if (ws_size >= 12877824ULL)  { SK1 = 1; SK2 = 8; useH1P = false; }
    else                              { SK1 = 1; SK2 = 1; useH1P = false; }

    deg_k<false><<<8192, 256, 0, stream>>>(ADJ, dvec, nullptr);
    gemm_old_k<64, 256, 1, 4, true, true, 1><<<128, 256, 0, stream>>>(
        W1, 512, X, 512, B1, 8192, dvec, 4, 32, 512, 0);
    if (useH1P) {
        gemm_old_k<64, 256, 1, 4, true, false, 0><<<128 * SK1, 256, 0, stream>>>(
            ADJ, 8192, B1, 8192, H1P, 256, dvec, 128, 1, 8192 / SK1, 2097152LL);
        reduce1_k<<<2048, 256, 0, stream>>>(H1P, dvec, X1, SK1);
    } else {
        gemm_old_k<64, 256, 1, 4, true, false, 2><<<128, 256, 0, stream>>>(
            ADJ, 8192, B1, 8192, X1, 256, dvec, 128, 1, 8192, 0);
    }
    gemm_old_k<16, 256, 1, 4, true, false, 1><<<32, 256, 0, stream>>>(
        W2, 256, X1, 256, B2, 8192, dvec, 1, 32, 256, 0);
    gemm_old_k<128, 16, 4, 1, true, false, 0><<<64 * SK2, 256, 0, stream>>>(
        ADJ, 8192, B2, 8192, H2P, 16, dvec, 64, 1, 8192 / SK2, 131072LL);
    final_k<<<32, 256, 0, stream>>>(H2P, dvec, out, SK2, 1.0f);
}

// Round 12
// 116.527 us; speedup vs baseline: 1.0144x; 1.0144x over previous
//
#include <hip/hip_runtime.h>

typedef __attribute__((ext_vector_type(8))) short bf16x8;   // 8 bf16
typedef __attribute__((ext_vector_type(4))) float f32x4;    // MFMA acc (16x16)
typedef __attribute__((ext_vector_type(8))) int   i32x8;    // f8f6f4 operand
typedef unsigned short u16;
typedef unsigned int   u32;
typedef unsigned char  u8;

#define DEVI __device__ __forceinline__

// fp32 -> bf16 round-to-nearest-even
DEVI u16 f2bf(float f) {
    u32 u = __float_as_uint(f);
    u32 r = (u + 0x7FFFu + ((u >> 16) & 1u)) >> 16;
    return (u16)r;
}
DEVI u32 pk(float a, float b) {
    return (u32)f2bf(a) | ((u32)f2bf(b) << 16);
}
DEVI float bflo(u32 w) { return __uint_as_float((w & 0xFFFFu) << 16); }
DEVI float bfhi(u32 w) { return __uint_as_float(w & 0xFFFF0000u); }
// 4x fp32 -> 4x fp8 e4m3 (OCP) packed in one dword
DEVI u32 cvt8(float a, float b, float c, float d) {
    int w = 0;
    w = __builtin_amdgcn_cvt_pk_fp8_f32(a, b, w, false);
    w = __builtin_amdgcn_cvt_pk_fp8_f32(c, d, w, true);
    return (u32)w;
}
// fp4 e2m1 encode of x in [0,1) with block scale 2^-2: code for t = 4x,
// RTN onto levels {0,0.5,1,1.5,2,3,4} = codes 0..6 (level 6.0/code 7 unused).
DEVI u32 enc1(float x) {
    float t = x * 4.0f;
    u32 c;
    if (t < 1.75f) c = (u32)(int)(t + t + 0.5f);
    else           c = (t < 2.5f) ? 4u : ((t < 3.5f) ? 5u : 6u);
    return c;
}
DEVI u32 enc8(float4 a, float4 b) {   // 8 elems -> 8 nibbles, little-endian
    return enc1(a.x) | (enc1(a.y) << 4) | (enc1(a.z) << 8) | (enc1(a.w) << 12) |
           (enc1(b.x) << 16) | (enc1(b.y) << 20) | (enc1(b.z) << 24) |
           (enc1(b.w) << 28);
}
// async global->LDS, 16B per lane (global_load_lds_dwordx4)
DEVI void gld16(const void* g, void* l) {
    __builtin_amdgcn_global_load_lds(
        (const __attribute__((address_space(1))) u32*)g,
        (__attribute__((address_space(3))) u32*)l, 16, 0, 0);
}

#define SCALE_A 0x7D7D7D7D   // e8m0 2^-2 per 32-elem block (uniform -> opsel-immune)
#define SCALE_B 0x7F7F7F7F   // e8m0 1.0

// ---------------------------------------------------------------------------
// Kernel 1: d[i] = rsqrt(rowsum(adj)); write fp4 PRE-SWIZZLED adjacency.
// ADJH layout: row-major, 4096 B/row; per 64-B k-group (128 elems), 4 slots
// of 16 B; physical slot = logical ^ ((row>>1)&3)  [2-way-free on ds_read].
// ---------------------------------------------------------------------------
template<bool WRITE_H>
__global__ __launch_bounds__(256)
void deg_k(const float* __restrict__ adj, float* __restrict__ dvec,
           u8* __restrict__ adjh) {
    const int row = blockIdx.x;
    const int t   = threadIdx.x;
    const float4* p = (const float4*)(adj + (long long)row * 8192);
    float s = 0.f;
#pragma unroll
    for (int i = 0; i < 2; ++i) {
        int c = t + i * 256;                 // 16-elem chunk index in [0,512)
        float4 v0 = p[4 * c + 0];
        float4 v1 = p[4 * c + 1];
        float4 v2 = p[4 * c + 2];
        float4 v3 = p[4 * c + 3];
        s += (v0.x + v0.y) + (v0.z + v0.w) + (v1.x + v1.y) + (v1.z + v1.w) +
             (v2.x + v2.y) + (v2.z + v2.w) + (v3.x + v3.y) + (v3.z + v3.w);
        if constexpr (WRITE_H) {
            u32 w0 = enc8(v0, v1);           // elems 0..7  of chunk
            u32 w1 = enc8(v2, v3);           // elems 8..15
            int grp = c >> 3, qq = c & 7;    // 64B group, 8B sub-chunk
            int phys = (qq >> 1) ^ ((row >> 1) & 3);
            *(uint2*)(adjh + (long long)row * 4096 + grp * 64 + phys * 16 +
                      (qq & 1) * 8) = make_uint2(w0, w1);
        }
    }
#pragma unroll
    for (int off = 32; off; off >>= 1) s += __shfl_down(s, off, 64);
    __shared__ float red[4];
    if ((t & 63) == 0) red[t >> 6] = s;
    __syncthreads();
    if (t == 0) dvec[row] = 1.0f / sqrtf(red[0] + red[1] + red[2] + red[3]);
}

// ---------------------------------------------------------------------------
// Small MFMA GEMM, transposed output repack to fp8, pre-swizzled for the fp4
// aggregates' B-operand read patterns:
//   SWZ 0 (B1): 16B slots in 128B j-groups, physical = logical ^ (n&7)
//   SWZ 1 (B2): 32B slots in 128B j-groups, physical = logical ^ (n&3)
//   AMODE 0: A fp32.  AMODE 2: A = relu(d/64 * sum4 bf16 H1P parts).
// ---------------------------------------------------------------------------
template<int BM, int BN, int WM, int WN, int AMODE, int SC, int SWZ>
__global__ __launch_bounds__(256)
void gemmsw_k(const void* __restrict__ Ap, int lda,
              const float* __restrict__ Bp, int ldb,
              u8* __restrict__ Op, int ldo,
              const float* __restrict__ dvec,
              int mtiles, int ntiles, int klen) {
    constexpr int BK  = 64;
    constexpr int WTM = BM / WM, WTN = BN / WN;
    constexpr int FM  = WTM / 16, FN = WTN / 16;
    constexpr int SA  = BM * BK;   // u16 elements
    constexpr int SB  = BN * BK;
    __shared__ __align__(16) u16 lds[SA + SB];

    const int t   = threadIdx.x;
    const int mt  = blockIdx.x % mtiles;
    const int nt  = (blockIdx.x / mtiles) % ntiles;
    const int m0  = mt * BM;
    const int n0  = nt * BN;

    const int lane = t & 63, lrow = lane & 15, kg = lane >> 4;
    const int wave = t >> 6;
    const int wr0  = (wave % WM) * WTM;
    const int wc0  = (wave / WM) * WTN;

    f32x4 acc[FM][FN] = {};

    auto stage = [&](int k0) {
        char* AB = (char*)lds;
        char* BB = (char*)(lds + SA);
        if constexpr (AMODE == 0) {
            constexpr int NA = BM * 16 / 256;
#pragma unroll
            for (int i = 0; i < NA; ++i) {
                int idx = t + i * 256, r = idx >> 4, c = idx & 15;
                float4 v = *(const float4*)((const float*)Ap +
                            (long long)(m0 + r) * lda + k0 + c * 4);
                int off = r * 128 + ((((c >> 1) ^ (r & 7)) << 4) | ((c & 1) << 3));
                *(uint2*)(AB + off) = make_uint2(pk(v.x, v.y), pk(v.z, v.w));
            }
        } else {   // AMODE 2: fused 4-part BF16 reduce + relu + d/64
            constexpr int NA = BM * 8 / 256;
#pragma unroll
            for (int i = 0; i < NA; ++i) {
                int idx = t + i * 256, r = idx >> 3, j8 = idx & 7;
                const u16* base = (const u16*)Ap +
                                  (long long)(m0 + r) * lda + k0 + j8 * 8;
                float s[8] = {};
#pragma unroll
                for (int pp = 0; pp < 4; ++pp) {
                    uint4 v = *(const uint4*)(base + (long long)pp * 2097152);
                    s[0] += bflo(v.x); s[1] += bfhi(v.x);
                    s[2] += bflo(v.y); s[3] += bfhi(v.y);
                    s[4] += bflo(v.z); s[5] += bfhi(v.z);
                    s[6] += bflo(v.w); s[7] += bfhi(v.w);
                }
                float dv = dvec[m0 + r] * 0.015625f;
                uint4 w = make_uint4(
                    pk(fmaxf(s[0], 0.f) * dv, fmaxf(s[1], 0.f) * dv),
                    pk(fmaxf(s[2], 0.f) * dv, fmaxf(s[3], 0.f) * dv),
                    pk(fmaxf(s[4], 0.f) * dv, fmaxf(s[5], 0.f) * dv),
                    pk(fmaxf(s[6], 0.f) * dv, fmaxf(s[7], 0.f) * dv));
                *(uint4*)(AB + r * 128 + ((j8 ^ (r & 7)) << 4)) = w;
            }
        }
        {   // B fp32
            constexpr int NB = BN * 16 / 256;
#pragma unroll
            for (int i = 0; i < NB; ++i) {
                int idx = t + i * 256, r = idx >> 4, c = idx & 15;
                float4 v = *(const float4*)(Bp + (long long)(n0 + r) * ldb + k0 + c * 4);
                int off = r * 128 + ((((c >> 1) ^ (r & 7)) << 4) | ((c & 1) << 3));
                *(uint2*)(BB + off) = make_uint2(pk(v.x, v.y), pk(v.z, v.w));
            }
        }
    };

    auto compute = [&]() {
        const char* AB = (const char*)lds;
        const char* BB = (const char*)(lds + SA);
#pragma unroll
        for (int s = 0; s < 2; ++s) {
            bf16x8 a[FM]; bf16x8 b[FN];
#pragma unroll
            for (int f = 0; f < FM; ++f) {
                int r = wr0 + f * 16 + lrow;
                a[f] = *(const bf16x8*)(AB + r * 128 + (((s * 4 + kg) ^ (r & 7)) << 4));
            }
#pragma unroll
            for (int f = 0; f < FN; ++f) {
                int r = wc0 + f * 16 + lrow;
                b[f] = *(const bf16x8*)(BB + r * 128 + (((s * 4 + kg) ^ (r & 7)) << 4));
            }
#pragma unroll
            for (int i = 0; i < FM; ++i)
#pragma unroll
                for (int j = 0; j < FN; ++j)
                    acc[i][j] = __builtin_amdgcn_mfma_f32_16x16x32_bf16(
                        a[i], b[j], acc[i][j], 0, 0, 0);
        }
    };

    const int NT = klen / BK;
    for (int tt = 0; tt < NT; ++tt) {
        stage(tt * BK);
        __syncthreads();
        compute();
        __syncthreads();
    }

    // ---- transposed fp8 repack epilogue (LDS bounce, padded stride BN+1)
    __syncthreads();
    float* LF = (float*)lds;
    constexpr int LDSBYTES = (SA + SB) * 2;
    constexpr int LFS = BN + 1;
    constexpr int PHR = (BM * LFS * 4 <= LDSBYTES) ? BM : (BM / 2);
    static_assert(PHR * LFS * 4 <= LDSBYTES, "repack phase too big");
    constexpr int NPH = BM / PHR;
    constexpr int MG  = PHR / 16;
#pragma unroll
    for (int ph = 0; ph < NPH; ++ph) {
        if (ph) __syncthreads();
#pragma unroll
        for (int i = 0; i < FM; ++i) {
            int mlb = wr0 + i * 16 + kg * 4;
            if (mlb >= ph * PHR && mlb < (ph + 1) * PHR) {
#pragma unroll
                for (int rr = 0; rr < 4; ++rr) {
                    float dv = dvec[m0 + mlb + rr] * (float)SC;
#pragma unroll
                    for (int j = 0; j < FN; ++j)
                        LF[(mlb - ph * PHR + rr) * LFS + wc0 + j * 16 + lrow] =
                            acc[i][j][rr] * dv;
                }
            }
        }
        __syncthreads();
        constexpr int CHK = BN * MG;
#pragma unroll
        for (int it = 0; it < (CHK + 255) / 256; ++it) {
            int q = t + it * 256;
            if (q < CHK) {
                int n = q / MG, mg = q % MG;
                float f[16];
#pragma unroll
                for (int e = 0; e < 16; ++e) f[e] = LF[(mg * 16 + e) * LFS + n];
                uint4 w = make_uint4(cvt8(f[0], f[1], f[2], f[3]),
                                     cvt8(f[4], f[5], f[6], f[7]),
                                     cvt8(f[8], f[9], f[10], f[11]),
                                     cvt8(f[12], f[13], f[14], f[15]));
                int gj = (m0 >> 4) + ph * MG + mg;   // 16-elem chunk along j
                int ng = n0 + n;
                long long byte;
                if constexpr (SWZ == 0)
                    byte = (long long)ng * ldo + (gj >> 3) * 128 +
                           (((gj & 7) ^ (ng & 7)) << 4);
                else
                    byte = (long long)ng * ldo + (gj >> 3) * 128 +
                           ((((gj >> 1) & 3) ^ (ng & 3)) << 5) + ((gj & 1) << 4);
                *(uint4*)(Op + byte) = w;
            }
        }
    }
}

// ---------------------------------------------------------------------------
// Layer-1 aggregate, MX: H1P[kp][i][h] = bf16( sum_k adj_fp4[i,k] * b1_fp8[h,k] )
// mfma_scale_f32_16x16x128_f8f6f4, A=fp4 (cbsz=4, scale 2^-2), B=fp8 (blgp=0,
// scale 1.0). BM=64, BN=256, BK=128, 4 waves, gld16 dbuf, vmcnt(9).
// (R10 verbatim — measured-good, do not touch.)
// ---------------------------------------------------------------------------
__global__ __launch_bounds__(256)
void agg1f4_k(const u8* __restrict__ A, const u8* __restrict__ B,
              u16* __restrict__ Op, int mtiles, int klen, long long kstride) {
    constexpr int BK = 128;
    constexpr int ABUF = 64 * 64;          // 4096 B  (64 rows x 64 B fp4)
    constexpr int BBUF = 256 * 128;        // 32768 B (256 rows x 128 B fp8)
    constexpr int BUF  = ABUF + BBUF;      // 36864 B
    __shared__ __align__(16) u8 lds[2 * BUF];   // 72 KB -> 2 blocks/CU

    const int t  = threadIdx.x;
    const int mt = blockIdx.x % mtiles;
    const int kp = blockIdx.x / mtiles;
    const int m0 = mt * 64;
    const long long k00 = (long long)kp * klen;     // element offset along k
    const int lane = t & 63, lrow = lane & 15, kg = lane >> 4;
    const int wc0  = (t >> 6) * 64;

    f32x4 acc[4][4] = {};

    auto stage = [&](long long k0, int pb) {
        u8* dst = lds + pb * BUF;
        {   // A fp4: 256 chunks = 64 rows x 4 slots (global pre-swizzled)
            int c = t, r = c >> 2;
            gld16(A + (long long)(m0 + r) * 4096 + (k0 >> 1) + (c & 3) * 16,
                  dst + c * 16);
        }
#pragma unroll
        for (int i = 0; i < 8; ++i) {   // B fp8: 2048 chunks = 256 rows x 8 slots
            int cb = t + i * 256, rb = cb >> 3;
            gld16(B + (long long)rb * 8192 + k0 + (cb & 7) * 16,
                  dst + ABUF + cb * 16);
        }
    };

    auto compute = [&](int pb) {
        const u8* Ab = lds + pb * BUF;
        const u8* Bb = Ab + ABUF;
        i32x8 a[4], b[4];
#pragma unroll
        for (int f = 0; f < 4; ++f) {
            int ar = f * 16 + lrow;
            uint4 aw = *(const uint4*)(Ab + ar * 64 +
                        ((kg ^ ((ar >> 1) & 3)) << 4));
            a[f] = i32x8{(int)aw.x, (int)aw.y, (int)aw.z, (int)aw.w, 0, 0, 0, 0};
        }
#pragma unroll
        for (int f = 0; f < 4; ++f) {
            int rb = wc0 + f * 16 + lrow;
            uint4 b0 = *(const uint4*)(Bb + rb * 128 +
                         (((2 * kg) ^ (rb & 7)) << 4));
            uint4 b1 = *(const uint4*)(Bb + rb * 128 +
                         (((2 * kg + 1) ^ (rb & 7)) << 4));
            b[f] = i32x8{(int)b0.x, (int)b0.y, (int)b0.z, (int)b0.w,
                         (int)b1.x, (int)b1.y, (int)b1.z, (int)b1.w};
        }
#pragma unroll
        for (int i = 0; i < 4; ++i)
#pragma unroll
            for (int j = 0; j < 4; ++j)
                acc[i][j] = __builtin_amdgcn_mfma_scale_f32_16x16x128_f8f6f4(
                    a[i], b[j], acc[i][j], 4, 0, 0, SCALE_A, 0, SCALE_B);
    };

    stage(k00, 0);
    const int NT = klen / BK;
    for (int tt = 0; tt < NT; ++tt) {
        const int p = tt & 1;
        if (tt + 1 < NT) {
            stage(k00 + (long long)(tt + 1) * BK, p ^ 1);
            asm volatile("s_waitcnt vmcnt(9)" ::: "memory");
        } else {
            asm volatile("s_waitcnt vmcnt(0)" ::: "memory");
        }
        __builtin_amdgcn_s_barrier();
        compute(p);
        asm volatile("" ::: "memory");
        __builtin_amdgcn_s_barrier();
    }

#pragma unroll
    for (int i = 0; i < 4; ++i)
#pragma unroll
        for (int j = 0; j < 4; ++j)
#pragma unroll
            for (int rr = 0; rr < 4; ++rr) {
                int m = m0 + i * 16 + kg * 4 + rr;
                int n = wc0 + j * 16 + lrow;
                Op[kp * kstride + (long long)m * 256 + n] = f2bf(acc[i][j][rr]);
            }
}

// ---------------------------------------------------------------------------
// Layer-2 aggregate, MX (R10 verbatim): H2P[kp][i][c] = sum_k fp4A * fp8B
// BM=64, 16 cols, BK=128, split-K=4 (KLEN 2048), B prestaged whole (32 KB).
// R11's split-K=8 regressed (B2 re-read + launch tail) — reverted.
// ---------------------------------------------------------------------------
__global__ __launch_bounds__(256)
void agg2f4_k(const u8* __restrict__ A, const u8* __restrict__ B,
              float* __restrict__ Op, int mtiles) {
    constexpr int KLEN = 2048, BK = 128, NT = KLEN / BK;   // 16 steps
    constexpr int ABUF = 64 * 64;                          // 4096 B
    __shared__ __align__(16) u8 lds[2 * ABUF + 16 * 2048]; // 40 KB

    const int t  = threadIdx.x;
    const int mt = blockIdx.x % mtiles;
    const int kp = blockIdx.x / mtiles;
    const int m0 = mt * 64;
    const long long k00 = (long long)kp * KLEN;
    const int lane = t & 63, lrow = lane & 15, kg = lane >> 4;
    const int wr0  = (t >> 6) * 16;
    u8* Bl = lds + 2 * ABUF;

    // prestage whole B K-slice: 16 rows x 2048 B (pre-swizzled 32B slots)
#pragma unroll
    for (int i = 0; i < 8; ++i) {
        int c = t + i * 256, rb = c >> 7;
        gld16(B + (long long)rb * 8192 + k00 + (c & 127) * 16, Bl + c * 16);
    }

    auto stageA = [&](long long k0, int pb) {
        int c = t, r = c >> 2;
        gld16(A + (long long)(m0 + r) * 4096 + (k0 >> 1) + (c & 3) * 16,
              lds + pb * ABUF + c * 16);
    };

    f32x4 acc = {};
    stageA(k00, 0);
    for (int tt = 0; tt < NT; ++tt) {
        const int p = tt & 1;
        if (tt + 1 < NT) {
            stageA(k00 + (long long)(tt + 1) * BK, p ^ 1);
            asm volatile("s_waitcnt vmcnt(1)" ::: "memory");
        } else {
            asm volatile("s_waitcnt vmcnt(0)" ::: "memory");
        }
        __builtin_amdgcn_s_barrier();
        const u8* Ab = lds + p * ABUF;
        int ra = wr0 + lrow;
        uint4 aw = *(const uint4*)(Ab + ra * 64 + ((kg ^ ((ra >> 1) & 3)) << 4));
        i32x8 a = i32x8{(int)aw.x, (int)aw.y, (int)aw.z, (int)aw.w, 0, 0, 0, 0};
        const u8* bbase = Bl + lrow * 2048 + tt * 128 + ((kg ^ (lrow & 3)) << 5);
        uint4 b0 = *(const uint4*)(bbase);
        uint4 b1 = *(const uint4*)(bbase + 16);
        i32x8 b = i32x8{(int)b0.x, (int)b0.y, (int)b0.z, (int)b0.w,
                        (int)b1.x, (int)b1.y, (int)b1.z, (int)b1.w};
        acc = __builtin_amdgcn_mfma_scale_f32_16x16x128_f8f6f4(
                a, b, acc, 4, 0, 0, SCALE_A, 0, SCALE_B);
        asm volatile("" ::: "memory");
        __builtin_amdgcn_s_barrier();
    }

#pragma unroll
    for (int rr = 0; rr < 4; ++rr) {
        int m = m0 + wr0 + kg * 4 + rr;
        Op[(long long)kp * 131072 + (long long)m * 16 + lrow] = acc[rr];
    }
}

// ---------------------------------------------------------------------------
// out[i][c] = log_softmax(scl * d[i] * sum_p H2p[p][i][c])
// ---------------------------------------------------------------------------
__global__ __launch_bounds__(256)
void final_k(const float* __restrict__ H, const float* __restrict__ dvec,
             float* __restrict__ out, int parts, float scl) {
    int i = blockIdx.x * 256 + threadIdx.x;
    float z[16];
#pragma unroll
    for (int c = 0; c < 16; c += 4) {
        float4 v = *(const float4*)(H + (long long)i * 16 + c);
        z[c] = v.x; z[c + 1] = v.y; z[c + 2] = v.z; z[c + 3] = v.w;
    }
    for (int p = 1; p < parts; ++p) {
#pragma unroll
        for (int c = 0; c < 16; c += 4) {
            float4 v = *(const float4*)(H + (long long)p * 131072 +
                                        (long long)i * 16 + c);
            z[c] += v.x; z[c + 1] += v.y; z[c + 2] += v.z; z[c + 3] += v.w;
        }
    }
    float dv = dvec[i] * scl;
    float m = -1e30f;
#pragma unroll
    for (int c = 0; c < 16; ++c) { z[c] *= dv; m = fmaxf(m, z[c]); }
    float l = 0.f;
#pragma unroll
    for (int c = 0; c < 16; ++c) l += __expf(z[c] - m);
    float lse = m + __logf(l);
#pragma unroll
    for (int c = 0; c < 16; c += 4) {
        float4 v;
        v.x = z[c] - lse; v.y = z[c + 1] - lse;
        v.z = z[c + 2] - lse; v.w = z[c + 3] - lse;
        *(float4*)(out + (long long)i * 16 + c) = v;
    }
}

// ===========================================================================
// Fallback path (small workspace): R2's bf16 kernels, kept verbatim.
// ===========================================================================
template<int BM, int BN, int WM, int WN, bool AF32, bool BF32, int EPI>
__global__ __launch_bounds__(256)
void gemm_old_k(const void* __restrict__ Ap, int lda,
                const void* __restrict__ Bp, int ldb,
                void* __restrict__ Op, int ldo,
                const float* __restrict__ dvec,
                int mtiles, int ntiles, int klen, long long kstride) {
    constexpr int BK  = 64;
    constexpr int WTM = BM / WM, WTN = BN / WN;
    constexpr int FM  = WTM / 16, FN = WTN / 16;
    constexpr int SA  = BM * BK;
    constexpr int SB  = BN * BK;
    __shared__ __align__(16) u16 lds[SA + SB];

    const int t   = threadIdx.x;
    const int bid = blockIdx.x;
    const int mt  = bid % mtiles;
    const int nt  = (bid / mtiles) % ntiles;
    const int kp  = bid / (mtiles * ntiles);
    const int m0  = mt * BM, n0 = nt * BN;
    const long long k00 = (long long)kp * klen;

    const float* Af = (const float*)Ap;
    const u16*   Ah = (const u16*)Ap;
    const float* Bf = (const float*)Bp;
    const u16*   Bh = (const u16*)Bp;

    f32x4 acc[FM][FN] = {};

    const int lane = t & 63;
    const int lrow = lane & 15, kg = lane >> 4;
    const int wave = t >> 6;
    const int wr0  = (wave % WM) * WTM;
    const int wc0  = (wave / WM) * WTN;

    auto stage = [&](long long k0) {
        char* AB = (char*)lds;
        char* BB = (char*)(lds + SA);
        if constexpr (AF32) {
            constexpr int NA = BM * 16 / 256;
#pragma unroll
            for (int i = 0; i < NA; ++i) {
                int idx = t + i * 256, r = idx >> 4, c = idx & 15;
                float4 v = *(const float4*)(Af + (long long)(m0 + r) * lda + k0 + c * 4);
                int off = r * 128 + ((((c >> 1) ^ (r & 7)) << 4) | ((c & 1) << 3));
                *(uint2*)(AB + off) = make_uint2(pk(v.x, v.y), pk(v.z, v.w));
            }
        } else {
            constexpr int NA = (BM * 8 + 255) / 256;
#pragma unroll
            for (int i = 0; i < NA; ++i) {
                int idx = t + i * 256;
                if (BM * 8 >= 256 || idx < BM * 8) {
                    int r = idx >> 3, j = idx & 7;
                    uint4 v = *(const uint4*)(Ah + (long long)(m0 + r) * lda + k0 + j * 8);
                    *(uint4*)(AB + r * 128 + ((j ^ (r & 7)) << 4)) = v;
                }
            }
        }
        if constexpr (BF32) {
            constexpr int NB = BN * 16 / 256;
#pragma unroll
            for (int i = 0; i < NB; ++i) {
                int idx = t + i * 256, r = idx >> 4, c = idx & 15;
                float4 v = *(const float4*)(Bf + (long long)(n0 + r) * ldb + k0 + c * 4);
                int off = r * 128 + ((((c >> 1) ^ (r & 7)) << 4) | ((c & 1) << 3));
                *(uint2*)(BB + off) = make_uint2(pk(v.x, v.y), pk(v.z, v.w));
            }
        } else {
            constexpr int NB = (BN * 8 + 255) / 256;
#pragma unroll
            for (int i = 0; i < NB; ++i) {
                int idx = t + i * 256;
                if (BN * 8 >= 256 || idx < BN * 8) {
                    int r = idx >> 3, j = idx & 7;
                    uint4 v = *(const uint4*)(Bh + (long long)(n0 + r) * ldb + k0 + j * 8);
                    *(uint4*)(BB + r * 128 + ((j ^ (r & 7)) << 4)) = v;
                }
            }
        }
    };

    auto compute = [&]() {
        const char* AB = (const char*)lds;
        const char* BB = (const char*)(lds + SA);
#pragma unroll
        for (int s = 0; s < 2; ++s) {
            bf16x8 a[FM]; bf16x8 b[FN];
#pragma unroll
            for (int f = 0; f < FM; ++f) {
                int r = wr0 + f * 16 + lrow;
                a[f] = *(const bf16x8*)(AB + r * 128 + (((s * 4 + kg) ^ (r & 7)) << 4));
            }
#pragma unroll
            for (int f = 0; f < FN; ++f) {
                int r = wc0 + f * 16 + lrow;
                b[f] = *(const bf16x8*)(BB + r * 128 + (((s * 4 + kg) ^ (r & 7)) << 4));
            }
#pragma unroll
            for (int i = 0; i < FM; ++i)
#pragma unroll
                for (int j = 0; j < FN; ++j)
                    acc[i][j] = __builtin_amdgcn_mfma_f32_16x16x32_bf16(
                        a[i], b[j], acc[i][j], 0, 0, 0);
        }
    };

    const int NT = klen / BK;
    for (int tt = 0; tt < NT; ++tt) {
        stage(k00 + (long long)tt * BK);
        __syncthreads();
        compute();
        __syncthreads();
    }

#pragma unroll
    for (int i = 0; i < FM; ++i)
#pragma unroll
        for (int j = 0; j < FN; ++j)
#pragma unroll
            for (int r = 0; r < 4; ++r) {
                int m = m0 + wr0 + i * 16 + kg * 4 + r;
                int n = n0 + wc0 + j * 16 + lrow;
                float v = acc[i][j][r];
                if constexpr (EPI == 0) {
                    ((float*)Op)[kp * kstride + (long long)m * ldo + n] = v;
                } else if constexpr (EPI == 1) {
                    ((u16*)Op)[(long long)m * ldo + n] = f2bf(v * dvec[n]);
                } else {
                    ((u16*)Op)[(long long)m * ldo + n] =
                        f2bf(fmaxf(v * dvec[m], 0.0f));
                }
            }
}

__global__ __launch_bounds__(256)
void reduce1_k(const float* __restrict__ H, const float* __restrict__ dvec,
               u16* __restrict__ x1, int parts) {
    long long i = ((long long)blockIdx.x * 256 + threadIdx.x) * 4;
    float4 s = *(const float4*)(H + i);
    for (int p = 1; p < parts; ++p) {
        float4 v = *(const float4*)(H + (long long)p * 2097152 + i);
        s.x += v.x; s.y += v.y; s.z += v.z; s.w += v.w;
    }
    float dv = dvec[i >> 8];
    *(uint2*)(x1 + i) = make_uint2(
        pk(fmaxf(s.x * dv, 0.f), fmaxf(s.y * dv, 0.f)),
        pk(fmaxf(s.z * dv, 0.f), fmaxf(s.w * dv, 0.f)));
}

// ---------------------------------------------------------------------------
extern "C" void kernel_launch(void* const* d_in, const int* in_sizes, int n_in,
                              void* d_out, int out_size, void* d_ws, size_t ws_size,
                              hipStream_t stream) {
    (void)in_sizes; (void)n_in; (void)out_size;
    const float* X   = (const float*)d_in[0];   // [8192,512]
    const float* ADJ = (const float*)d_in[1];   // [8192,8192]
    const float* W1  = (const float*)d_in[2];   // [256,512]
    const float* W2  = (const float*)d_in[3];   // [16,256]
    float* out = (float*)d_out;
    char*  ws  = (char*)d_ws;

    if (ws_size >= 54689792ULL) {
        // ---- fast path (R10-best, 116.5us): MX-fp4 adjacency + scaled MFMA
        float* dvec = (float*)(ws + 0);           //  32 KB
        u8*    B1   = (u8*)(ws + 32768);          //   2 MB [256 h][8192 j] fp8 swz
        u8*    B2   = (u8*)(ws + 2129920);        // 128 KB [16 c][8192 j] fp8 swz
        u16*   H1P  = (u16*)(ws + 2260992);       //  16 MB [4][8192][256] bf16
        float* H2P  = (float*)(ws + 19038208);    //   2 MB [4][8192][16]
        u8*    ADJH = (u8*)(ws + 21135360);       //  32 MB [8192][4096 B] fp4 swz

        // 1) degrees + fp4 swizzled adjacency
        deg_k<true><<<8192, 256, 0, stream>>>(ADJ, dvec, ADJH);

        // 2) B1[h][j] = fp8(64 * d_j * (X @ W1^T)[j,h]) — SWZ0 (B1-read pattern)
        gemmsw_k<64, 128, 1, 4, 0, 64, 0><<<256, 256, 0, stream>>>(
            X, 512, W1, 512, B1, 8192, dvec, 128, 2, 512);

        // 3) H1P = ADJH(fp4) @ B1^T(fp8), bf16 partials (split-K=4)
        agg1f4_k<<<512, 256, 0, stream>>>(ADJH, B1, H1P, 128, 2048, 2097152LL);

        // 4) B2[c][j] = fp8(8192 * d_j * relu(d/64 * sum4 H1P) @ W2^T) — SWZ1
        gemmsw_k<64, 16, 4, 1, 2, 8192, 1><<<128, 256, 0, stream>>>(
            H1P, 256, W2, 256, B2, 8192, dvec, 128, 1, 256);

        // 5) H2P = ADJH(fp4) @ B2^T(fp8)  (split-K=4, 512 blocks — R10)
        agg2f4_k<<<512, 256, 0, stream>>>(ADJH, B2, H2P, 128);

        // 6) d_i/8192 scale + log-softmax (4 parts)
        final_k<<<32, 256, 0, stream>>>(H2P, dvec, out, 4, 1.0f / 8192.0f);
        return;
    }

    // ---- fallback: fp32-adjacency bf16 path (R2 structure)
    float* dvec = (float*)(ws + 0);
    u16*   B1   = (u16*)(ws + 32768);
    u16*   X1   = (u16*)(ws + 4227072);
    u16*   B2   = (u16*)(ws + 8421376);
    float* H2P  = (float*)(ws + 8683520);
    float* H1P  = (float*)(ws + 12877824);

    int SK1, SK2; bool useH1P;
    if      (ws_size >= 46432256ULL)  { SK1 = 4; SK2 = 8; useH1P = true;  }
    else if (ws_size >= 29655040ULL)  { SK1 = 2; SK2 = 8; useH1P = true;  }
    else if (ws_size >= 12877824ULL)  { SK1 = 1; SK2 = 8; useH1P = false; }
    else                              { SK1 = 1; SK2 = 1; useH1P = false; }

    deg_k<false><<<8192, 256, 0, stream>>>(ADJ, dvec, nullptr);
    gemm_old_k<64, 256, 1, 4, true, true, 1><<<128, 256, 0, stream>>>(
        W1, 512, X, 512, B1, 8192, dvec, 4, 32, 512, 0);
    if (useH1P) {
        gemm_old_k<64, 256, 1, 4, true, false, 0><<<128 * SK1, 256, 0, stream>>>(
            ADJ, 8192, B1, 8192, H1P, 256, dvec, 128, 1, 8192 / SK1, 2097152LL);
        reduce1_k<<<2048, 256, 0, stream>>>(H1P, dvec, X1, SK1);
    } else {
        gemm_old_k<64, 256, 1, 4, true, false, 2><<<128, 256, 0, stream>>>(
            ADJ, 8192, B1, 8192, X1, 256, dvec, 128, 1, 8192, 0);
    }
    gemm_old_k<16, 256, 1, 4, true, false, 1><<<32, 256, 0, stream>>>(
        W2, 256, X1, 256, B2, 8192, dvec, 1, 32, 256, 0);
    gemm_old_k<128, 16, 4, 1, true, false, 0><<<64 * SK2, 256, 0, stream>>>(
        ADJ, 8192, B2, 8192, H2P, 16, dvec, 64, 1, 8192 / SK2, 131072LL);
    final_k<<<32, 256, 0, stream>>>(H2P, dvec, out, SK2, 1.0f);
}